// Round 11
// baseline (3021.266 us; speedup 1.0000x reference)
//
#include <hip/hip_runtime.h>
#include <cstdint>

#define Hn 36
#define G4 144          // 4*H gate rows
#define TT 512
#define BB 2048

__device__ __forceinline__ float sigf(float x) { return 1.0f / (1.0f + __expf(-x)); }
__device__ __forceinline__ float tanh_fast(float x) {
    float e = __expf(2.0f * x);          // exact +-1 limits via over/underflow
    return 1.0f - 2.0f / (e + 1.0f);
}

// ---- K1 named-register weight quads (kept: K1 measured ~400us, not the wall)
#define REP9(M, P)  M(P,0) M(P,1) M(P,2) M(P,3) M(P,4) M(P,5) M(P,6) M(P,7) M(P,8)
#define DECLQ(P, i) float P##i##x, P##i##y, P##i##z, P##i##w;
#define LOADQ(P, i) { float4 _t = wp[i]; P##i##x = _t.x; P##i##y = _t.y; P##i##z = _t.z; P##i##w = _t.w; }
#define PINQ(P, i)  asm volatile("" : "+v"(P##i##x), "+v"(P##i##y), "+v"(P##i##z), "+v"(P##i##w));
#define FMAQ(P, i)                                                        \
    {  float4 hv = *(const float4*)&hb[(i) * 4];                          \
       z0 = fmaf(P##i##x, hv.x, z0); z1 = fmaf(P##i##y, hv.y, z1);        \
       z2 = fmaf(P##i##z, hv.z, z2); z3 = fmaf(P##i##w, hv.w, z3); }

// array-based dots (fallback kernel only)
#define DOT36(W, H, Z0, Z1, Z2, Z3)                        \
    do {                                                   \
        _Pragma("unroll") for (int _k = 0; _k < 9; ++_k) { \
            float4 hv = *(const float4*)&(H)[_k * 4];      \
            Z0 = fmaf((W)[_k * 4 + 0], hv.x, Z0);          \
            Z1 = fmaf((W)[_k * 4 + 1], hv.y, Z1);          \
            Z2 = fmaf((W)[_k * 4 + 2], hv.z, Z2);          \
            Z3 = fmaf((W)[_k * 4 + 3], hv.w, Z3);          \
        }                                                  \
    } while (0)

#define DOT72(W, H, Z0, Z1, Z2, Z3)                         \
    do {                                                    \
        _Pragma("unroll") for (int _k = 0; _k < 18; ++_k) { \
            float4 hv = *(const float4*)&(H)[_k * 4];       \
            Z0 = fmaf((W)[_k * 4 + 0], hv.x, Z0);           \
            Z1 = fmaf((W)[_k * 4 + 1], hv.y, Z1);           \
            Z2 = fmaf((W)[_k * 4 + 2], hv.z, Z2);           \
            Z3 = fmaf((W)[_k * 4 + 3], hv.w, Z3);           \
        }                                                   \
    } while (0)

// ============ K1: layer-0 REVERSE scan, full batch -> h0r (151 MB ws) ========
#define SG1 4
#define NTK1 (SG1 * G4)   // 576
__global__ __launch_bounds__(NTK1) void l0rev_kernel(
    const float* __restrict__ x,
    const float* __restrict__ Wih, const float* __restrict__ Whh,
    const float* __restrict__ bih, const float* __restrict__ bhh,
    float* __restrict__ h0r)
{
    const int tid = threadIdx.x;
    const int cc  = tid / G4;
    const int g   = tid % G4;
    const int b   = blockIdx.x * SG1 + cc;

    __shared__ float xs[SG1][TT];
    __shared__ float hs[SG1][40];
    __shared__ float zs[SG1][G4];

    for (int i = g; i < TT; i += G4) xs[cc][i] = x[(size_t)b * TT + i];

    REP9(DECLQ, R)
    {
        const float4* wp = (const float4*)(Whh + g * Hn);
        REP9(LOADQ, R)
    }
    float wx   = Wih[g];
    float bias = bih[g] + bhh[g];
    REP9(PINQ, R)
    asm volatile("" : "+v"(wx), "+v"(bias));

    if (g < 40) hs[cc][g] = 0.0f;
    float c = 0.0f;
    __syncthreads();

    float* dst = h0r + (size_t)b * TT * Hn;

    for (int s = 0; s < TT; ++s) {
        const int t = TT - 1 - s;
        float z0 = fmaf(xs[cc][t], wx, bias), z1 = 0.f, z2 = 0.f, z3 = 0.f;
        {
            const float* hb = hs[cc];
            REP9(FMAQ, R)
        }
        zs[cc][g] = (z0 + z1) + (z2 + z3);
        __syncthreads();
        if (g < Hn) {
            float zi = zs[cc][g], zf = zs[cc][g + 36], zg = zs[cc][g + 72], zo = zs[cc][g + 108];
            c = sigf(zf) * c + sigf(zi) * tanh_fast(zg);
            float h = sigf(zo) * tanh_fast(c);
            hs[cc][g] = h;
            dst[(size_t)t * Hn + g] = h;
        }
        __syncthreads();
    }
}

// ===== K2: skewed fusion, 4 chains/block, weights re-read from L1 per step ===
// Non-hoistable asm batch load: 9x global_load_dwordx4 + one vmcnt(0).
#define WLOAD9()                                                            \
    asm volatile(                                                           \
        "global_load_dwordx4 %0, %9, off\n\t"                               \
        "global_load_dwordx4 %1, %9, off offset:16\n\t"                     \
        "global_load_dwordx4 %2, %9, off offset:32\n\t"                     \
        "global_load_dwordx4 %3, %9, off offset:48\n\t"                     \
        "global_load_dwordx4 %4, %9, off offset:64\n\t"                     \
        "global_load_dwordx4 %5, %9, off offset:80\n\t"                     \
        "global_load_dwordx4 %6, %9, off offset:96\n\t"                     \
        "global_load_dwordx4 %7, %9, off offset:112\n\t"                    \
        "global_load_dwordx4 %8, %9, off offset:128\n\t"                    \
        "s_waitcnt vmcnt(0)"                                                \
        : "=v"(w0), "=v"(w1), "=v"(w2), "=v"(w3), "=v"(w4),                 \
          "=v"(w5), "=v"(w6), "=v"(w7), "=v"(w8)                            \
        : "v"(wbase))

// one weight quad applied to all 4 chains (hb = base of 4x40-float h bank)
#define DOT4(WQ, OFF)                                                       \
    {   float4 h0q = *(const float4*)&hb[0 * 40 + (OFF)];                   \
        A0 = fmaf(WQ.x, h0q.x, A0); A1 = fmaf(WQ.y, h0q.y, A1);             \
        A2 = fmaf(WQ.z, h0q.z, A2); A3 = fmaf(WQ.w, h0q.w, A3);             \
        float4 h1q = *(const float4*)&hb[1 * 40 + (OFF)];                   \
        B0 = fmaf(WQ.x, h1q.x, B0); B1 = fmaf(WQ.y, h1q.y, B1);             \
        B2 = fmaf(WQ.z, h1q.z, B2); B3 = fmaf(WQ.w, h1q.w, B3);             \
        float4 h2q = *(const float4*)&hb[2 * 40 + (OFF)];                   \
        C0 = fmaf(WQ.x, h2q.x, C0); C1 = fmaf(WQ.y, h2q.y, C1);             \
        C2 = fmaf(WQ.z, h2q.z, C2); C3 = fmaf(WQ.w, h2q.w, C3);             \
        float4 h3q = *(const float4*)&hb[3 * 40 + (OFF)];                   \
        D0 = fmaf(WQ.x, h3q.x, D0); D1 = fmaf(WQ.y, h3q.y, D1);             \
        D2 = fmaf(WQ.z, h3q.z, D2); D3 = fmaf(WQ.w, h3q.w, D3); }

#define SG2 4
#define NT2 576
__global__ __launch_bounds__(NT2, 5) void fused_fl_kernel(
    const float* __restrict__ x,
    const float* __restrict__ Wih0f, const float* __restrict__ Whh0f,
    const float* __restrict__ bih0f, const float* __restrict__ bhh0f,
    const float* __restrict__ Wih1f, const float* __restrict__ Whh1f,
    const float* __restrict__ bih1f, const float* __restrict__ bhh1f,
    const float* __restrict__ Wih1r,
    const float* __restrict__ bih1r, const float* __restrict__ bhh1r,
    const float* __restrict__ fcW, const float* __restrict__ fcb,
    const float* __restrict__ h0r,
    float* __restrict__ out)
{
    const int tid  = threadIdx.x;
    const int gp   = tid / G4;     // 0:F(Whh0f)  1:L(Wih1f lo, h0f)  2:L(Wih1f hi, h0r)  3:L(Whh1f, h1)
    const int g    = tid % G4;     // gate row
    const int cc   = g / Hn;       // combine-lane chain (0..3)
    const int ii   = g % Hn;       // combine-lane unit  (0..35)
    const int base = blockIdx.x * SG2;

    __shared__ float xs[SG2][TT + 1];
    __shared__ float h0f[2][SG2][40];
    __shared__ float h0rs[2][SG2][40];
    __shared__ float h1s[SG2][40];
    __shared__ float zF[SG2][G4];
    __shared__ float zL[3][SG2][G4];
    __shared__ float red[SG2][40];

    for (int i = tid; i < SG2 * (TT + 1); i += NT2) {
        int c = i / (TT + 1), t = i % (TT + 1);
        xs[c][t] = (t < TT) ? x[(size_t)(base + c) * TT + t] : 0.0f;
    }
    for (int i = tid; i < 2 * SG2 * 40; i += NT2) {
        (&h0f[0][0][0])[i] = 0.0f;
        (&h0rs[0][0][0])[i] = 0.0f;
    }
    for (int i = tid; i < SG2 * 40; i += NT2) (&h1s[0][0])[i] = 0.0f;

    const float* wbase = (gp == 0) ? (Whh0f + g * Hn)
                       : (gp == 1) ? (Wih1f + g * 72)
                       : (gp == 2) ? (Wih1f + g * 72 + 36)
                                   : (Whh1f + g * Hn);
    float wx0  = (gp == 0) ? Wih0f[g] : 0.0f;
    float bsum = (gp == 0) ? (bih0f[g] + bhh0f[g])
               : (gp == 3) ? (bih1f[g] + bhh1f[g]) : 0.0f;

    const float* srow = h0r + (size_t)(base + cc) * TT * Hn + ii;   // gp2 stream
    float c0 = 0.0f, c1 = 0.0f;
    __syncthreads();

    // ---- prologue: gp0 dot for h0f(0); gp2 stages h0r(0) & prefetches h0r(1)
    float rv = 0.0f;
    if (gp == 0) {
#pragma unroll
        for (int c = 0; c < SG2; ++c) zF[c][g] = fmaf(xs[c][0], wx0, bsum);
    } else if (gp == 2) {
        h0rs[0][cc][ii] = srow[0];
        rv = srow[Hn];                        // h0r(1)
    }
    __syncthreads();
    if (gp == 0) {
        float zi = zF[cc][ii], zg = zF[cc][ii + 72], zo = zF[cc][ii + 108];
        c0 = sigf(zi) * tanh_fast(zg);        // c=0 start: forget term vanishes
        h0f[0][cc][ii] = sigf(zo) * tanh_fast(c0);
    }
    __syncthreads();

    int cur = 0;
    for (int t = 0; t < TT; ++t) {
        float rv2 = (gp == 2 && t + 2 < TT) ? srow[(size_t)(t + 2) * Hn] : 0.0f;

        const float* hb = (gp <= 1) ? &h0f[cur][0][0]
                        : (gp == 2) ? &h0rs[cur][0][0] : &h1s[0][0];
        float A0, B0, C0, D0;
        if (gp == 0) {
            A0 = fmaf(xs[0][t + 1], wx0, bsum);
            B0 = fmaf(xs[1][t + 1], wx0, bsum);
            C0 = fmaf(xs[2][t + 1], wx0, bsum);
            D0 = fmaf(xs[3][t + 1], wx0, bsum);
        } else {
            A0 = bsum; B0 = bsum; C0 = bsum; D0 = bsum;   // bsum=0 for gp1/2
        }
        float A1 = 0.f, A2 = 0.f, A3 = 0.f, B1 = 0.f, B2 = 0.f, B3 = 0.f;
        float C1 = 0.f, C2 = 0.f, C3 = 0.f, D1 = 0.f, D2 = 0.f, D3 = 0.f;

        float4 w0, w1, w2, w3, w4, w5, w6, w7, w8;
        WLOAD9();
        DOT4(w0, 0)  DOT4(w1, 4)  DOT4(w2, 8)  DOT4(w3, 12) DOT4(w4, 16)
        DOT4(w5, 20) DOT4(w6, 24) DOT4(w7, 28) DOT4(w8, 32)

        float zA = (A0 + A1) + (A2 + A3);
        float zB = (B0 + B1) + (B2 + B3);
        float zC = (C0 + C1) + (C2 + C3);
        float zD = (D0 + D1) + (D2 + D3);
        if (gp == 0) {
            zF[0][g] = zA; zF[1][g] = zB; zF[2][g] = zC; zF[3][g] = zD;
        } else {
            float* zt = &zL[gp - 1][0][0];
            zt[0 * G4 + g] = zA; zt[1 * G4 + g] = zB;
            zt[2 * G4 + g] = zC; zt[3 * G4 + g] = zD;
        }
        __syncthreads();

        if (gp == 0) {
            if (t + 1 < TT) {                  // produce h0f(t+1)
                float zi = zF[cc][ii],       zf = zF[cc][ii + 36];
                float zg = zF[cc][ii + 72],  zo = zF[cc][ii + 108];
                c0 = sigf(zf) * c0 + sigf(zi) * tanh_fast(zg);
                h0f[cur ^ 1][cc][ii] = sigf(zo) * tanh_fast(c0);
            }
        } else if (gp == 3) {                  // produce h1(t)
            float zi = zL[0][cc][ii]       + zL[1][cc][ii]       + zL[2][cc][ii];
            float zf = zL[0][cc][ii + 36]  + zL[1][cc][ii + 36]  + zL[2][cc][ii + 36];
            float zg = zL[0][cc][ii + 72]  + zL[1][cc][ii + 72]  + zL[2][cc][ii + 72];
            float zo = zL[0][cc][ii + 108] + zL[1][cc][ii + 108] + zL[2][cc][ii + 108];
            c1 = sigf(zf) * c1 + sigf(zi) * tanh_fast(zg);
            h1s[cc][ii] = sigf(zo) * tanh_fast(c1);
        } else if (gp == 2 && t + 1 < TT) {
            h0rs[cur ^ 1][cc][ii] = rv;        // stage h0r(t+1)
        }
        __syncthreads();
        rv = rv2;
        if (t + 1 < TT) cur ^= 1;
    }

    // ---- tail: L1 reverse single step at t=T-1 (h0=c0=0) + FC ----
    {   // thread (chain=gp, row=g): full 72-dim dot vs [h0f | h0r](T-1)
        float zR = bih1r[g] + bhh1r[g];
        const float* wr = Wih1r + g * 72;
#pragma unroll
        for (int k = 0; k < Hn; ++k) zR = fmaf(wr[k],      h0f[cur][gp][k],  zR);
#pragma unroll
        for (int k = 0; k < Hn; ++k) zR = fmaf(wr[36 + k], h0rs[cur][gp][k], zR);
        zF[gp][g] = zR;
    }
    __syncthreads();
    if (tid < SG2 * Hn) {
        int c = tid / Hn, i = tid % Hn;
        float zi = zF[c][i], zg = zF[c][i + 72], zo = zF[c][i + 108];
        float cR = sigf(zi) * tanh_fast(zg);   // c0=0: forget term vanishes
        float hR = sigf(zo) * tanh_fast(cR);
        red[c][i] = fcW[36 + i] * hR + fcW[i] * h1s[c][i];
    }
    __syncthreads();
    if (tid < SG2) {
        float s2 = fcb[0];
        for (int j = 0; j < Hn; ++j) s2 += red[tid][j];
        out[base + tid] = s2;
    }
}

// ================= FALLBACK PATH (zero workspace, ckpt/recompute) ============
__global__ __launch_bounds__(G4, 1) void fused_all_kernel(
    const float* __restrict__ x,
    const float* __restrict__ Wih0f, const float* __restrict__ Whh0f,
    const float* __restrict__ bih0f, const float* __restrict__ bhh0f,
    const float* __restrict__ Wih0r, const float* __restrict__ Whh0r,
    const float* __restrict__ bih0r, const float* __restrict__ bhh0r,
    const float* __restrict__ Wih1f, const float* __restrict__ Whh1f,
    const float* __restrict__ bih1f, const float* __restrict__ bhh1f,
    const float* __restrict__ Wih1r,
    const float* __restrict__ bih1r, const float* __restrict__ bhh1r,
    const float* __restrict__ fcW, const float* __restrict__ fcb,
    float* __restrict__ out)
{
    const int g = threadIdx.x;
    const int b = blockIdx.x;

    __shared__ float xs[TT];
    __shared__ float cbuf[64][Hn];
    __shared__ float ckpt_h[8][Hn], ckpt_c[8][Hn];
    __shared__ float hr[40], h0s[80], hs1[40], zs[G4], red[40];

    for (int i = g; i < TT; i += G4) xs[i] = x[(size_t)b * TT + i];

    float wr[Hn], wf[Hn];
#pragma unroll
    for (int k = 0; k < Hn; ++k) wr[k] = Whh0r[g * Hn + k];
#pragma unroll
    for (int k = 0; k < Hn; ++k) wf[k] = Whh0f[g * Hn + k];
    const float wxr = Wih0r[g], br = bih0r[g] + bhh0r[g];
    const float wxf = Wih0f[g], bf = bih0f[g] + bhh0f[g];
    float w1i[72];
#pragma unroll
    for (int k = 0; k < 72; ++k) w1i[k] = Wih1f[g * 72 + k];
    float w1h[Hn];
#pragma unroll
    for (int k = 0; k < Hn; ++k) w1h[k] = Whh1f[g * Hn + k];
    const float b1 = bih1f[g] + bhh1f[g];

    if (g < Hn) hr[g] = 0.0f;
    float cr = 0.0f;
    __syncthreads();
    for (int s = 0; s < TT; ++s) {
        const int t = TT - 1 - s;
        if ((t & 63) == 63 && g < Hn) { ckpt_h[t >> 6][g] = hr[g]; ckpt_c[t >> 6][g] = cr; }
        float z0 = fmaf(xs[t], wxr, br), z1 = 0.f, z2 = 0.f, z3 = 0.f;
        DOT36(wr, hr, z0, z1, z2, z3);
        zs[g] = (z0 + z1) + (z2 + z3);
        __syncthreads();
        if (g < Hn) {
            float zi = zs[g], zf = zs[g + 36], zg = zs[g + 72], zo = zs[g + 108];
            cr = sigf(zf) * cr + sigf(zi) * tanh_fast(zg);
            hr[g] = sigf(zo) * tanh_fast(cr);
        }
        __syncthreads();
    }

    if (g < Hn) { h0s[g] = 0.0f; hs1[g] = 0.0f; }
    float c0 = 0.0f, c1 = 0.0f;
    __syncthreads();

    for (int m = 0; m < 8; ++m) {
        if (g < Hn) { hr[g] = ckpt_h[m][g]; cr = ckpt_c[m][g]; }
        __syncthreads();
        for (int j = 0; j < 64; ++j) {
            const int t = m * 64 + 63 - j;
            float z0 = fmaf(xs[t], wxr, br), z1 = 0.f, z2 = 0.f, z3 = 0.f;
            DOT36(wr, hr, z0, z1, z2, z3);
            zs[g] = (z0 + z1) + (z2 + z3);
            __syncthreads();
            if (g < Hn) {
                float zi = zs[g], zf = zs[g + 36], zg = zs[g + 72], zo = zs[g + 108];
                cr = sigf(zf) * cr + sigf(zi) * tanh_fast(zg);
                float h = sigf(zo) * tanh_fast(cr);
                hr[g] = h;
                cbuf[t & 63][g] = h;
            }
            __syncthreads();
        }
        for (int j = 0; j < 64; ++j) {
            const int t = m * 64 + j;
            float z0 = fmaf(xs[t], wxf, bf), z1 = 0.f, z2 = 0.f, z3 = 0.f;
            DOT36(wf, h0s, z0, z1, z2, z3);
            zs[g] = (z0 + z1) + (z2 + z3);
            __syncthreads();
            if (g < Hn) {
                float zi = zs[g], zf = zs[g + 36], zg = zs[g + 72], zo = zs[g + 108];
                c0 = sigf(zf) * c0 + sigf(zi) * tanh_fast(zg);
                h0s[g] = sigf(zo) * tanh_fast(c0);
            } else if (g < 72) {
                h0s[g] = cbuf[j][g - 36];
            }
            __syncthreads();
            float y0 = b1, y1 = 0.f, y2 = 0.f, y3 = 0.f;
            DOT72(w1i, h0s, y0, y1, y2, y3);
            DOT36(w1h, hs1, y0, y1, y2, y3);
            zs[g] = (y0 + y1) + (y2 + y3);
            __syncthreads();
            if (g < Hn) {
                float zi = zs[g], zf = zs[g + 36], zg = zs[g + 72], zo = zs[g + 108];
                c1 = sigf(zf) * c1 + sigf(zi) * tanh_fast(zg);
                hs1[g] = sigf(zo) * tanh_fast(c1);
            }
            __syncthreads();
        }
    }

    float zR = bih1r[g] + bhh1r[g];
#pragma unroll
    for (int k = 0; k < 72; ++k) zR = fmaf(Wih1r[g * 72 + k], h0s[k], zR);
    zs[g] = zR;
    __syncthreads();
    if (g < Hn) {
        float zi = zs[g], zg = zs[g + 72], zo = zs[g + 108];
        float c  = sigf(zi) * tanh_fast(zg);
        float hrv = sigf(zo) * tanh_fast(c);
        red[g] = fcW[36 + g] * hrv + fcW[g] * hs1[g];
    }
    __syncthreads();
    if (g == 0) {
        float s = fcb[0];
        for (int j = 0; j < Hn; ++j) s += red[j];
        out[b] = s;
    }
}

extern "C" void kernel_launch(void* const* d_in, const int* in_sizes, int n_in,
                              void* d_out, int out_size, void* d_ws, size_t ws_size,
                              hipStream_t stream)
{
    const float* x     = (const float*)d_in[0];
    const float* Wih0f = (const float*)d_in[1];
    const float* Whh0f = (const float*)d_in[2];
    const float* bih0f = (const float*)d_in[3];
    const float* bhh0f = (const float*)d_in[4];
    const float* Wih0r = (const float*)d_in[5];
    const float* Whh0r = (const float*)d_in[6];
    const float* bih0r = (const float*)d_in[7];
    const float* bhh0r = (const float*)d_in[8];
    const float* Wih1f = (const float*)d_in[9];
    const float* Whh1f = (const float*)d_in[10];
    const float* bih1f = (const float*)d_in[11];
    const float* bhh1f = (const float*)d_in[12];
    const float* Wih1r = (const float*)d_in[13];
    const float* bih1r = (const float*)d_in[15];
    const float* bhh1r = (const float*)d_in[16];
    const float* fcW   = (const float*)d_in[17];
    const float* fcb   = (const float*)d_in[18];

    const size_t need = (size_t)BB * TT * Hn * sizeof(float);   // 151 MB (known-safe)
    if (d_ws != nullptr && ws_size >= need) {
        float* h0r = (float*)d_ws;
        l0rev_kernel<<<BB / SG1, NTK1, 0, stream>>>(x, Wih0r, Whh0r, bih0r, bhh0r, h0r);
        fused_fl_kernel<<<BB / SG2, NT2, 0, stream>>>(
            x, Wih0f, Whh0f, bih0f, bhh0f, Wih1f, Whh1f, bih1f, bhh1f,
            Wih1r, bih1r, bhh1r, fcW, fcb, h0r, (float*)d_out);
    } else {
        fused_all_kernel<<<BB, G4, 0, stream>>>(
            x, Wih0f, Whh0f, bih0f, bhh0f, Wih0r, Whh0r, bih0r, bhh0r,
            Wih1f, Whh1f, bih1f, bhh1f, Wih1r, bih1r, bhh1r, fcW, fcb,
            (float*)d_out);
    }
}